// Round 2
// baseline (164.476 us; speedup 1.0000x reference)
//
#include <hip/hip_runtime.h>
#include <stdint.h>

// SpMM sum-reduce, N_ROWS=100000, DEG=16 fixed, F=64, fp32 in/out.
//
// Round 4: XCD-sliced bf16 gather table.
// Established so far:
//  - The 256 MiB d_ws poison fill (~43us) is UNCONDITIONAL (round 1: present
//    even with d_ws untouched) -> using d_ws is free. Table lives in d_ws.
//  - The spmm is L3-random-BW bound: table (12.8 MB bf16) >> 4 MB per-XCD L2,
//    so ~70% of the 205 MB gather stream misses L2 and is served by L3 at
//    ~3.1 TB/s effective (prev session: 179 MB @ 57us fp32; bf16 ~140MB@~40us).
// Fix: partition the feature dim into 4 groups of 16 feats (32 B/row/group),
// store the table GROUP-MAJOR, and exploit round-robin blockIdx%8 -> XCD
// dispatch: blocks with (bid&7)>>1 == g only gather from slice g (3.2 MB),
// which stays resident in that XCD's private 4 MB L2. Gathers become L2 hits.

#define FDIM 64

// ---- fp32 -> bf16 RNE pack of two floats into one u32 ----
__device__ __forceinline__ uint32_t pack_bf16(float lo, float hi) {
    uint32_t x = __float_as_uint(lo), y = __float_as_uint(hi);
    x = (x + 0x7fffu + ((x >> 16) & 1u)) >> 16;
    y = (y + 0x7fffu + ((y >> 16) & 1u)) >> 16;
    return x | (y << 16);
}

#define BF_LO(w) __uint_as_float((w) << 16)
#define BF_HI(w) __uint_as_float((w) & 0xffff0000u)

// ---------------- fp32 -> bf16 transposed-table conversion ----------------
// table layout: [4 groups][n_cols][2 x uint4]  (32 B = 16 bf16 feats per row)
// thread t: col = t>>2, g = t&3. Reads 64 B contiguous, writes 32 B into slice.
__global__ __launch_bounds__(256) void cvt_transpose_kernel(
    const float4* __restrict__ in,    // [n_cols][16] float4
    uint4*        __restrict__ table, // [4][n_cols][2] uint4
    int n_cols)
{
    const int t = blockIdx.x * blockDim.x + threadIdx.x;
    if (t >= n_cols * 4) return;
    const int c = t >> 2;
    const int g = t & 3;
    const float4* src = in + (size_t)c * 16 + g * 4;
    const float4 a = src[0], b = src[1], d = src[2], e = src[3];
    uint4 q0, q1;
    q0.x = pack_bf16(a.x, a.y); q0.y = pack_bf16(a.z, a.w);
    q0.z = pack_bf16(b.x, b.y); q0.w = pack_bf16(b.z, b.w);
    q1.x = pack_bf16(d.x, d.y); q1.y = pack_bf16(d.z, d.w);
    q1.z = pack_bf16(e.x, e.y); q1.w = pack_bf16(e.z, e.w);
    uint4* dst = table + (size_t)g * n_cols * 2 + (size_t)c * 2;
    dst[0] = q0;
    dst[1] = q1;
}

// ---------------- XCD-sliced SpMM ----------------
// Block geometry: 256 threads, 1 thread = 1 (row, group).
//   g   = (bid & 7) >> 1     -> feature group 0..3 (2 XCDs per group)
//   row = (bid >> 3)*512 + (bid & 1)*256 + tid
// Each thread accumulates 16 fp32 feats; per edge: 2 x 16B gathers from a
// 3.2 MB L2-resident slice.
__global__ __launch_bounds__(256) void spmm_deg16_sliced_kernel(
    const int*   __restrict__ rowptr,
    const int*   __restrict__ col,
    const float* __restrict__ value,
    const uint4* __restrict__ table,  // [4][n_cols][2] uint4
    float4*      __restrict__ out4,   // [N_ROWS][16] float4
    int n_rows, int n_cols)
{
    const int bid = blockIdx.x;
    const int g   = (bid & 7) >> 1;
    const int row = (bid >> 3) * 512 + (bid & 1) * 256 + (int)threadIdx.x;
    if (row >= n_rows) return;

    const uint4* __restrict__ slice = table + (size_t)g * n_cols * 2;

    const int start = rowptr[row];
    const int end   = rowptr[row + 1];
    const int deg   = end - start;

    float acc[16];
    #pragma unroll
    for (int k = 0; k < 16; ++k) acc[k] = 0.f;

    if (deg == 16 && (start & 3) == 0) {
        // vector-load the row's 16 (col, value)
        const int4*   c4p = (const int4*)  (col   + start);
        const float4* v4p = (const float4*)(value + start);
        int   ci[16];
        float vi[16];
        #pragma unroll
        for (int j = 0; j < 4; ++j) {
            int4   c = c4p[j];
            float4 v = v4p[j];
            ci[4*j+0] = c.x; ci[4*j+1] = c.y; ci[4*j+2] = c.z; ci[4*j+3] = c.w;
            vi[4*j+0] = v.x; vi[4*j+1] = v.y; vi[4*j+2] = v.z; vi[4*j+3] = v.w;
        }

        // 4 batches of 4 edges; 8 gathers (32B/edge) in flight per batch
        #pragma unroll
        for (int h = 0; h < 4; ++h) {
            uint4 q[8];
            #pragma unroll
            for (int e = 0; e < 4; ++e) {
                const size_t base = (size_t)ci[4*h + e] * 2;
                q[2*e + 0] = slice[base + 0];
                q[2*e + 1] = slice[base + 1];
            }
            #pragma unroll
            for (int e = 0; e < 4; ++e) {
                const float v = vi[4*h + e];
                const uint4 q0 = q[2*e + 0];
                const uint4 q1 = q[2*e + 1];
                acc[ 0] += v * BF_LO(q0.x);  acc[ 1] += v * BF_HI(q0.x);
                acc[ 2] += v * BF_LO(q0.y);  acc[ 3] += v * BF_HI(q0.y);
                acc[ 4] += v * BF_LO(q0.z);  acc[ 5] += v * BF_HI(q0.z);
                acc[ 6] += v * BF_LO(q0.w);  acc[ 7] += v * BF_HI(q0.w);
                acc[ 8] += v * BF_LO(q1.x);  acc[ 9] += v * BF_HI(q1.x);
                acc[10] += v * BF_LO(q1.y);  acc[11] += v * BF_HI(q1.y);
                acc[12] += v * BF_LO(q1.z);  acc[13] += v * BF_HI(q1.z);
                acc[14] += v * BF_LO(q1.w);  acc[15] += v * BF_HI(q1.w);
            }
        }
    } else {
        // generic CSR path
        for (int e = start; e < end; ++e) {
            const size_t base = (size_t)col[e] * 2;
            const uint4 q0 = slice[base + 0];
            const uint4 q1 = slice[base + 1];
            const float v  = value[e];
            acc[ 0] += v * BF_LO(q0.x);  acc[ 1] += v * BF_HI(q0.x);
            acc[ 2] += v * BF_LO(q0.y);  acc[ 3] += v * BF_HI(q0.y);
            acc[ 4] += v * BF_LO(q0.z);  acc[ 5] += v * BF_HI(q0.z);
            acc[ 6] += v * BF_LO(q0.w);  acc[ 7] += v * BF_HI(q0.w);
            acc[ 8] += v * BF_LO(q1.x);  acc[ 9] += v * BF_HI(q1.x);
            acc[10] += v * BF_LO(q1.y);  acc[11] += v * BF_HI(q1.y);
            acc[12] += v * BF_LO(q1.z);  acc[13] += v * BF_HI(q1.z);
            acc[14] += v * BF_LO(q1.w);  acc[15] += v * BF_HI(q1.w);
        }
    }

    // write this thread's 16 contiguous feats (64 B) of row `row`
    float4* dst = out4 + (size_t)row * (FDIM / 4) + g * 4;
    dst[0] = make_float4(acc[ 0], acc[ 1], acc[ 2], acc[ 3]);
    dst[1] = make_float4(acc[ 4], acc[ 5], acc[ 6], acc[ 7]);
    dst[2] = make_float4(acc[ 8], acc[ 9], acc[10], acc[11]);
    dst[3] = make_float4(acc[12], acc[13], acc[14], acc[15]);
}

// ---------------- fp32 fallback (if ws too small) ----------------
__global__ __launch_bounds__(256) void spmm_deg16_f32_kernel(
    const int*    __restrict__ rowptr,
    const int*    __restrict__ col,
    const float*  __restrict__ value,
    const float4* __restrict__ other4,
    float4*       __restrict__ out4,
    int n_rows)
{
    const int tid = blockIdx.x * blockDim.x + threadIdx.x;
    const int row = tid >> 4;
    const int fi  = tid & 15;
    if (row >= n_rows) return;
    const int start = rowptr[row];
    const int end   = rowptr[row + 1];
    float4 acc = make_float4(0.f, 0.f, 0.f, 0.f);
    for (int e = start; e < end; ++e) {
        const float4 o = other4[(size_t)col[e] * 16 + fi];
        const float  v = value[e];
        acc.x += v * o.x; acc.y += v * o.y; acc.z += v * o.z; acc.w += v * o.w;
    }
    out4[(size_t)row * 16 + fi] = acc;
}

extern "C" void kernel_launch(void* const* d_in, const int* in_sizes, int n_in,
                              void* d_out, int out_size, void* d_ws, size_t ws_size,
                              hipStream_t stream) {
    const int*   rowptr = (const int*)  d_in[0];
    const int*   col    = (const int*)  d_in[1];
    const float* value  = (const float*)d_in[2];
    const float* other  = (const float*)d_in[3];
    float*       out    = (float*)      d_out;

    const int       n_rows  = in_sizes[0] - 1;
    const long long n_other = in_sizes[3];        // n_cols * FDIM elements
    const int       n_cols  = (int)(n_other / FDIM);
    const size_t ws_needed  = (size_t)n_other * 2; // bf16 table bytes

    if (ws_size >= ws_needed && (n_other % FDIM) == 0) {
        // Phase 1: fp32 -> bf16 group-major table in d_ws
        const int t1 = n_cols * 4;
        cvt_transpose_kernel<<<(t1 + 255) / 256, 256, 0, stream>>>(
            (const float4*)other, (uint4*)d_ws, n_cols);

        // Phase 2: XCD-sliced SpMM. 8 consecutive blocks = 4 groups x 512 rows.
        const int nblocks = 8 * ((n_rows + 511) / 512);
        spmm_deg16_sliced_kernel<<<nblocks, 256, 0, stream>>>(
            rowptr, col, value, (const uint4*)d_ws, (float4*)out,
            n_rows, n_cols);
    } else {
        const int t = n_rows * 16;
        spmm_deg16_f32_kernel<<<(t + 255) / 256, 256, 0, stream>>>(
            rowptr, col, value, (const float4*)other, (float4*)out, n_rows);
    }
}

// Round 3
// 132.864 us; speedup vs baseline: 1.2379x; 1.2379x over previous
//
#include <hip/hip_runtime.h>
#include <stdint.h>

// SpMM sum-reduce, N_ROWS=100000, DEG=16 fixed, F=64, fp32 in/out.
//
// Round 5: XCD-sliced bf16 table, COALESCED lane-pair gathers.
// Established:
//  - 256 MiB d_ws poison fill (~44us) is unconditional -> d_ws is free to use.
//  - Full-table gathers are L3-random-BW bound (~102 MB L2-miss @ ~3.1 TB/s
//    ~= 33us) -> round-0 spmm ~40us.
//  - Round-2 feature-slicing (1 lane/row, 2x16B scattered) made gathers
//    L2-resident but went request-bound: 64 scattered segments per wave-load,
//    79.5us, VALUBusy 6%. Coalescing matters as much as residency.
// This round: 4 feature groups (32 B/row/group, 3.2 MB slice resident in the
// XCD-pair's private L2 via bid%8 round-robin) x 2 lanes per edge reading
// contiguous 16 B each -> one aligned 32 B segment per edge-instance.
// Segments: 6.4M all-L2-hit (vs 3.2M half-L3 in round-0, 12.8M in round-2).

#define FDIM 64

// ---- fp32 -> bf16 RNE pack of two floats into one u32 ----
__device__ __forceinline__ uint32_t pack_bf16(float lo, float hi) {
    uint32_t x = __float_as_uint(lo), y = __float_as_uint(hi);
    x = (x + 0x7fffu + ((x >> 16) & 1u)) >> 16;
    y = (y + 0x7fffu + ((y >> 16) & 1u)) >> 16;
    return x | (y << 16);
}

#define BF_LO(w) __uint_as_float((w) << 16)
#define BF_HI(w) __uint_as_float((w) & 0xffff0000u)

// ---------------- fp32 -> bf16 transposed-table conversion ----------------
// table layout: [4 groups][n_cols][2 x uint4]  (32 B = 16 bf16 feats per row)
// group g holds feats [16g, 16g+16); slice[c*2+h] = feats [16g+8h, 16g+8h+8).
__global__ __launch_bounds__(256) void cvt_transpose_kernel(
    const float4* __restrict__ in,    // [n_cols][16] float4
    uint4*        __restrict__ table, // [4][n_cols][2] uint4
    int n_cols)
{
    const int t = blockIdx.x * blockDim.x + threadIdx.x;
    if (t >= n_cols * 4) return;
    const int c = t >> 2;
    const int g = t & 3;
    const float4* src = in + (size_t)c * 16 + g * 4;
    const float4 a = src[0], b = src[1], d = src[2], e = src[3];
    uint4 q0, q1;
    q0.x = pack_bf16(a.x, a.y); q0.y = pack_bf16(a.z, a.w);
    q0.z = pack_bf16(b.x, b.y); q0.w = pack_bf16(b.z, b.w);
    q1.x = pack_bf16(d.x, d.y); q1.y = pack_bf16(d.z, d.w);
    q1.z = pack_bf16(e.x, e.y); q1.w = pack_bf16(e.z, e.w);
    uint4* dst = table + (size_t)g * n_cols * 2 + (size_t)c * 2;
    dst[0] = q0;
    dst[1] = q1;
}

// ---------------- XCD-sliced SpMM, lane-pair coalesced ----------------
// Block geometry: 256 threads; thread = (row_local, half).
//   g    = (bid & 7) >> 1                      -> feature group 0..3
//   row  = (bid >> 3)*256 + (bid & 1)*128 + (tid >> 1)
//   half = tid & 1                             -> which 16 B of the 32 B slice row
// 8 consecutive blocks cover 256 rows x all 4 groups; bid%8 round-robins the
// 8 XCDs so group g's 3.2 MB slice lives in XCDs {2g, 2g+1} L2 only.
__global__ __launch_bounds__(256) void spmm_deg16_pair_kernel(
    const int*   __restrict__ rowptr,
    const int*   __restrict__ col,
    const float* __restrict__ value,
    const uint4* __restrict__ table,  // [4][n_cols][2] uint4
    float4*      __restrict__ out4,   // [N_ROWS][16] float4
    int n_rows, int n_cols)
{
    const int bid  = blockIdx.x;
    const int g    = (bid & 7) >> 1;
    const int tid  = (int)threadIdx.x;
    const int row  = (bid >> 3) * 256 + (bid & 1) * 128 + (tid >> 1);
    const int half = tid & 1;
    if (row >= n_rows) return;

    const uint4* __restrict__ slice = table + (size_t)g * n_cols * 2 + half;

    const int start = rowptr[row];
    const int end   = rowptr[row + 1];
    const int deg   = end - start;

    float acc[8];
    #pragma unroll
    for (int k = 0; k < 8; ++k) acc[k] = 0.f;

    if (deg == 16 && (start & 3) == 0) {
        // vector-load the row's 16 (col, value)
        const int4*   c4p = (const int4*)  (col   + start);
        const float4* v4p = (const float4*)(value + start);
        int   ci[16];
        float vi[16];
        #pragma unroll
        for (int j = 0; j < 4; ++j) {
            int4   c = c4p[j];
            float4 v = v4p[j];
            ci[4*j+0] = c.x; ci[4*j+1] = c.y; ci[4*j+2] = c.z; ci[4*j+3] = c.w;
            vi[4*j+0] = v.x; vi[4*j+1] = v.y; vi[4*j+2] = v.z; vi[4*j+3] = v.w;
        }

        // two batches of 8 gathers held in flight; lanes 2e/2e+1 fetch a
        // contiguous, 32B-aligned pair of uint4 from the same table row
        #pragma unroll
        for (int h = 0; h < 2; ++h) {
            uint4 q[8];
            #pragma unroll
            for (int j = 0; j < 8; ++j)
                q[j] = slice[(size_t)ci[8*h + j] * 2];
            #pragma unroll
            for (int j = 0; j < 8; ++j) {
                const float v = vi[8*h + j];
                const uint32_t w0 = q[j].x, w1 = q[j].y, w2 = q[j].z, w3 = q[j].w;
                acc[0] += v * BF_LO(w0);  acc[1] += v * BF_HI(w0);
                acc[2] += v * BF_LO(w1);  acc[3] += v * BF_HI(w1);
                acc[4] += v * BF_LO(w2);  acc[5] += v * BF_HI(w2);
                acc[6] += v * BF_LO(w3);  acc[7] += v * BF_HI(w3);
            }
        }
    } else {
        // generic CSR path
        for (int e = start; e < end; ++e) {
            const uint4 q = slice[(size_t)col[e] * 2];
            const float v = value[e];
            acc[0] += v * BF_LO(q.x);  acc[1] += v * BF_HI(q.x);
            acc[2] += v * BF_LO(q.y);  acc[3] += v * BF_HI(q.y);
            acc[4] += v * BF_LO(q.z);  acc[5] += v * BF_HI(q.z);
            acc[6] += v * BF_LO(q.w);  acc[7] += v * BF_HI(q.w);
        }
    }

    // thread writes 8 feats = 32 B: out[row][16g + 8*half .. +8)
    const size_t base = (size_t)row * (FDIM / 4) + g * 4 + half * 2;
    out4[base + 0] = make_float4(acc[0], acc[1], acc[2], acc[3]);
    out4[base + 1] = make_float4(acc[4], acc[5], acc[6], acc[7]);
}

// ---------------- fp32 fallback (if ws too small) ----------------
__global__ __launch_bounds__(256) void spmm_deg16_f32_kernel(
    const int*    __restrict__ rowptr,
    const int*    __restrict__ col,
    const float*  __restrict__ value,
    const float4* __restrict__ other4,
    float4*       __restrict__ out4,
    int n_rows)
{
    const int tid = blockIdx.x * blockDim.x + threadIdx.x;
    const int row = tid >> 4;
    const int fi  = tid & 15;
    if (row >= n_rows) return;
    const int start = rowptr[row];
    const int end   = rowptr[row + 1];
    float4 acc = make_float4(0.f, 0.f, 0.f, 0.f);
    for (int e = start; e < end; ++e) {
        const float4 o = other4[(size_t)col[e] * 16 + fi];
        const float  v = value[e];
        acc.x += v * o.x; acc.y += v * o.y; acc.z += v * o.z; acc.w += v * o.w;
    }
    out4[(size_t)row * 16 + fi] = acc;
}

extern "C" void kernel_launch(void* const* d_in, const int* in_sizes, int n_in,
                              void* d_out, int out_size, void* d_ws, size_t ws_size,
                              hipStream_t stream) {
    const int*   rowptr = (const int*)  d_in[0];
    const int*   col    = (const int*)  d_in[1];
    const float* value  = (const float*)d_in[2];
    const float* other  = (const float*)d_in[3];
    float*       out    = (float*)      d_out;

    const int       n_rows  = in_sizes[0] - 1;
    const long long n_other = in_sizes[3];        // n_cols * FDIM elements
    const int       n_cols  = (int)(n_other / FDIM);
    const size_t ws_needed  = (size_t)n_other * 2; // bf16 table bytes

    if (ws_size >= ws_needed && (n_other % FDIM) == 0) {
        // Phase 1: fp32 -> bf16 group-major table in d_ws
        const int t1 = n_cols * 4;
        cvt_transpose_kernel<<<(t1 + 255) / 256, 256, 0, stream>>>(
            (const float4*)other, (uint4*)d_ws, n_cols);

        // Phase 2: sliced SpMM. 8 consecutive blocks = 4 groups x 256 rows.
        const int nblocks = 8 * ((n_rows + 255) / 256);
        spmm_deg16_pair_kernel<<<nblocks, 256, 0, stream>>>(
            rowptr, col, value, (const uint4*)d_ws, (float4*)out,
            n_rows, n_cols);
    } else {
        const int t = n_rows * 16;
        spmm_deg16_f32_kernel<<<(t + 255) / 256, 256, 0, stream>>>(
            rowptr, col, value, (const float4*)other, (float4*)out, n_rows);
    }
}